// Round 15
// baseline (140.201 us; speedup 1.0000x reference)
//
#include <hip/hip_runtime.h>
#include <hip/hip_bf16.h>

#define KNBR 20
typedef unsigned short u16;
typedef __attribute__((ext_vector_type(8))) short bf16x8;   // 8 bf16 = 4 VGPR
typedef __attribute__((ext_vector_type(4))) float f32x4;    // MFMA C/D frag

// async global->LDS, 16B/lane; LDS dest wave-uniform base + lane*16 (m104)
#define GLDS16(gsrc, ldst)                                                     \
    __builtin_amdgcn_global_load_lds(                                          \
        (const __attribute__((address_space(1))) unsigned int*)(const void*)(gsrc), \
        (__attribute__((address_space(3))) unsigned int*)(void*)(ldst), 16, 0, 0)

// ---- runtime index-width detection (proven round 5) ----
__device__ __forceinline__ bool idx_is64(const unsigned int* w) {
    return (w[1] | w[3] | w[5] | w[7] | w[9] | w[11] | w[13] | w[15]) == 0u;
}
__device__ __forceinline__ int idx_at(const int* p, bool is64, long long i) {
    return is64 ? p[2 * i] : p[i];
}
__device__ __forceinline__ u16 f2bf(float x) {
    union { __hip_bfloat16 b; u16 u; } cv;
    cv.b = __float2bfloat16(x);
    return cv.u;
}
__device__ __forceinline__ float blo2f(unsigned int w) {
    union { float f; unsigned int i; } c; c.i = w << 16; return c.f;
}
__device__ __forceinline__ float bhi2f(unsigned int w) {
    union { float f; unsigned int i; } c; c.i = w & 0xffff0000u; return c.f;
}

// ---------------- K0: all fp32->bf16 casts in one kernel ----------------
__global__ void __launch_bounds__(256) k_cast(
    const float* __restrict__ X, const float* __restrict__ Wn,
    const float* __restrict__ Wf, u16* __restrict__ Xb,
    u16* __restrict__ Wnb, u16* __restrict__ Wfb, int nx4)
{
    const int i = blockIdx.x * 256 + threadIdx.x;
    const float4* src; ushort4* dst; int j;
    if (i < nx4)                     { src = (const float4*)X;  dst = (ushort4*)Xb;  j = i; }
    else if (i < nx4 + 16384)        { src = (const float4*)Wn; dst = (ushort4*)Wnb; j = i - nx4; }
    else if (i < nx4 + 16384 + 32768){ src = (const float4*)Wf; dst = (ushort4*)Wfb; j = i - nx4 - 16384; }
    else return;
    const float4 v = src[j];
    ushort4 o;
    o.x = f2bf(v.x); o.y = f2bf(v.y); o.z = f2bf(v.z); o.w = f2bf(v.w);
    dst[j] = o;
}

// ---------------- K1: fused gather+mean -> GEMM1 -> GEMM2 -> normalize ------
// Round-15: BM=32 (was 64) to cut LDS 73KB -> 52.75KB -> 3 blocks/CU
// (round-14 counters: Occupancy 18.3%, all pipes idle -> TLP-starved,
// especially the latency-bound gather phase). 256 thr = 4 waves, each wave
// 32 rows x 64 cols. Full double-buffering kept.
__global__ void __launch_bounds__(256, 3) k_fused(
    const u16* __restrict__ Xb, const int* __restrict__ sub_nodes,
    const int* __restrict__ nbr, const int* __restrict__ g2s,
    const u16* __restrict__ Wnb, const float* __restrict__ bn,
    const u16* __restrict__ Wfb, const float* __restrict__ bfin,
    float* __restrict__ Out, int M)
{
    __shared__ u16 mh[32 * 256];                 // 16KB: mean, then h
    __shared__ u16 Bs[2][256 * 32];              // 16KB x2
    __shared__ u16 Xs[2][32 * 32];               // 2KB x2
    __shared__ __align__(16) float sums[32][4];  // 0.5KB

    const int t    = threadIdx.x;
    const int lane = t & 63;
    const int w    = t >> 6;             // wave 0..3 == N-chunk of 64 cols
    const int l15  = lane & 15;
    const int lk8  = (lane >> 4) << 3;   // 0,8,16,24
    const int rsub = (lane >> 4) << 2;   // 0,4,8,12
    const int r7   = l15 & 7;            // (row&7) for rows fm*16+l15
    const int r3   = l15 & 3;            // (row&3)
    const int sRow = lane >> 2;          // staging: row-in-group 0..15
    const int sSlot= lane & 3;           // staging: chunk 0..3
    const int m0   = blockIdx.x * 32;

// stage 16KB B-tile (256 rows x 32k), linear LDS, source chunk-swizzled c^(r&3)
#define STAGE_B(buf, Bp, KT, tt) do {                                          \
    _Pragma("unroll")                                                          \
    for (int rp_ = 0; rp_ < 4; ++rp_) {                                        \
        const int rr_ = (rp_ * 4 + w) * 16 + sRow;                             \
        const int cc_ = sSlot ^ (rr_ & 3);                                     \
        GLDS16(Bp + (size_t)rr_ * KT + (tt) * 32 + cc_ * 8,                    \
               &Bs[buf][(rp_ * 4 + w) * 512]);                                 \
    } } while (0)

// stage 2KB X-tile (32 rows x 32k): waves 0-1 only, 32 rows per wave-call
#define STAGE_X(buf, tt) do {                                                  \
    if (w < 2) {                                                               \
        const int rl_ = w * 16 + sRow;                                         \
        int rg_ = m0 + rl_; rg_ = (rg_ < M) ? rg_ : (M - 1);                   \
        const int cc_ = sSlot ^ (rl_ & 3);                                     \
        GLDS16(Xb + (size_t)rg_ * 256 + (tt) * 32 + cc_ * 8, &Xs[buf][w * 512]); \
    } } while (0)

    // prefetch GEMM1 B step 0 under the gather
    STAGE_B(0, Wnb, 256, 0);

    // ---- phase G: gather-mean for this block's 32 rows (2 rows/wave/iter) --
    {
        const bool is64 = idx_is64((const unsigned int*)nbr);
        const int half = lane >> 5;
        const int l31  = lane & 31;
        const int sb   = half << 5;
        #pragma unroll 1
        for (int j = 0; j < 4; ++j) {
            const int rl  = w * 8 + j * 2 + half;
            const int row = m0 + rl;
            const int rowc = (row < M) ? row : (M - 1);
            const int g = idx_at(sub_nodes, is64, rowc);
            int s_my = rowc;
            if (l31 < KNBR) {
                int nid = idx_at(nbr, is64, (long long)g * KNBR + l31);
                int s   = idx_at(g2s, is64, nid);
                s_my = (s < 0) ? rowc : s;
            }
            float a0=0.f,a1=0.f,a2=0.f,a3=0.f,a4=0.f,a5=0.f,a6=0.f,a7=0.f;
            #pragma unroll
            for (int k = 0; k < KNBR; ++k) {
                const int sk = __shfl(s_my, sb + k, 64);
                const uint4 v = *(const uint4*)(Xb + (size_t)sk * 256 + l31 * 8);
                a0 += blo2f(v.x); a1 += bhi2f(v.x);
                a2 += blo2f(v.y); a3 += bhi2f(v.y);
                a4 += blo2f(v.z); a5 += bhi2f(v.z);
                a6 += blo2f(v.w); a7 += bhi2f(v.w);
            }
            const float inv = 1.0f / (float)KNBR;
            uint4 o;
            o.x = (unsigned)f2bf(a0*inv) | ((unsigned)f2bf(a1*inv) << 16);
            o.y = (unsigned)f2bf(a2*inv) | ((unsigned)f2bf(a3*inv) << 16);
            o.z = (unsigned)f2bf(a4*inv) | ((unsigned)f2bf(a5*inv) << 16);
            o.w = (unsigned)f2bf(a6*inv) | ((unsigned)f2bf(a7*inv) << 16);
            *(uint4*)&mh[rl * 256 + ((l31 ^ (rl & 7)) << 3)] = o;
        }
    }
    __syncthreads();   // mean in LDS + B1[0] staged

    // ---- phase 1: h = relu(mean @ Wn^T + bn), h -> mh (in place) ----------
    f32x4 acc[2][4];
    #pragma unroll
    for (int i = 0; i < 2; ++i)
        #pragma unroll
        for (int j = 0; j < 4; ++j)
            acc[i][j] = (f32x4)(0.f);

    #pragma unroll
    for (int tt = 0; tt < 8; ++tt) {
        const int cur = tt & 1;
        if (tt < 7) STAGE_B(cur ^ 1, Wnb, 256, tt + 1);
        bf16x8 af[2], bfr[4];
        #pragma unroll
        for (int fm = 0; fm < 2; ++fm)
            af[fm] = *(const bf16x8*)&mh[(fm*16 + l15) * 256 +
                                         (((tt*4 + (lk8 >> 3)) ^ r7) << 3)];
        #pragma unroll
        for (int fn = 0; fn < 4; ++fn)
            bfr[fn] = *(const bf16x8*)&Bs[cur][(w*64 + fn*16 + l15) * 32 +
                                              (((lk8 >> 3) ^ r3) << 3)];
        #pragma unroll
        for (int fm = 0; fm < 2; ++fm)
            #pragma unroll
            for (int fn = 0; fn < 4; ++fn)
                acc[fm][fn] = __builtin_amdgcn_mfma_f32_16x16x32_bf16(
                    af[fm], bfr[fn], acc[fm][fn], 0, 0, 0);
        __syncthreads();
    }

    // prefetch GEMM2 step 0 (Bs[0] free after step 6's barrier; Xs untouched)
    STAGE_B(0, Wfb, 512, 0);
    STAGE_X(0, 0);

    // write h into mh (all mean reads completed at loop-end barrier)
    #pragma unroll
    for (int fn = 0; fn < 4; ++fn) {
        const int col = w * 64 + fn * 16 + l15;
        const float bv = bn[col];
        #pragma unroll
        for (int fm = 0; fm < 2; ++fm)
            #pragma unroll
            for (int r = 0; r < 4; ++r) {
                const int row = fm * 16 + rsub + r;
                const float v = fmaxf(acc[fm][fn][r] + bv, 0.f);
                mh[row * 256 + ((((col >> 3) ^ (row & 7))) << 3) + (col & 7)] = f2bf(v);
            }
    }
    __syncthreads();   // h visible + GEMM2 step-0 tiles staged

    // ---- phase 2: out = normalize(relu([X|h] @ Wf^T + bf)) ----------------
    #pragma unroll
    for (int i = 0; i < 2; ++i)
        #pragma unroll
        for (int j = 0; j < 4; ++j)
            acc[i][j] = (f32x4)(0.f);

    #pragma unroll
    for (int tt = 0; tt < 16; ++tt) {
        const int cur = tt & 1;
        if (tt < 15) {
            STAGE_B(cur ^ 1, Wfb, 512, tt + 1);
            if (tt + 1 < 8) STAGE_X(cur ^ 1, tt + 1);
        }
        bf16x8 af[2], bfr[4];
        if (tt < 8) {
            #pragma unroll
            for (int fm = 0; fm < 2; ++fm)
                af[fm] = *(const bf16x8*)&Xs[cur][(fm*16 + l15) * 32 +
                                                  (((lk8 >> 3) ^ r3) << 3)];
        } else {
            #pragma unroll
            for (int fm = 0; fm < 2; ++fm)
                af[fm] = *(const bf16x8*)&mh[(fm*16 + l15) * 256 +
                                             ((((tt-8)*4 + (lk8 >> 3)) ^ r7) << 3)];
        }
        #pragma unroll
        for (int fn = 0; fn < 4; ++fn)
            bfr[fn] = *(const bf16x8*)&Bs[cur][(w*64 + fn*16 + l15) * 32 +
                                              (((lk8 >> 3) ^ r3) << 3)];
        #pragma unroll
        for (int fm = 0; fm < 2; ++fm)
            #pragma unroll
            for (int fn = 0; fn < 4; ++fn)
                acc[fm][fn] = __builtin_amdgcn_mfma_f32_16x16x32_bf16(
                    af[fm], bfr[fn], acc[fm][fn], 0, 0, 0);
        __syncthreads();
    }

    // epilogue: bias + relu + row-L2-normalize + fp32 store
    float part[2][4];
    #pragma unroll
    for (int fm = 0; fm < 2; ++fm)
        #pragma unroll
        for (int r = 0; r < 4; ++r)
            part[fm][r] = 0.f;
    #pragma unroll
    for (int fn = 0; fn < 4; ++fn) {
        const float bv = bfin[w * 64 + fn * 16 + l15];
        #pragma unroll
        for (int fm = 0; fm < 2; ++fm)
            #pragma unroll
            for (int r = 0; r < 4; ++r) {
                const float v = fmaxf(acc[fm][fn][r] + bv, 0.f);
                acc[fm][fn][r] = v;
                part[fm][r] += v * v;
            }
    }
    #pragma unroll
    for (int fm = 0; fm < 2; ++fm)
        #pragma unroll
        for (int r = 0; r < 4; ++r) {
            float s = part[fm][r];
            s += __shfl_xor(s, 1, 64);
            s += __shfl_xor(s, 2, 64);
            s += __shfl_xor(s, 4, 64);
            s += __shfl_xor(s, 8, 64);
            part[fm][r] = s;
        }
    if (l15 == 0) {
        #pragma unroll
        for (int fm = 0; fm < 2; ++fm)
            #pragma unroll
            for (int r = 0; r < 4; ++r)
                sums[fm * 16 + rsub + r][w] = part[fm][r];
    }
    __syncthreads();
    #pragma unroll
    for (int fm = 0; fm < 2; ++fm)
        #pragma unroll
        for (int r = 0; r < 4; ++r) {
            const int lrow = fm * 16 + rsub + r;
            const f32x4 sv = *(const f32x4*)&sums[lrow][0];
            const float tot = sv.x + sv.y + sv.z + sv.w;
            const float scale = 1.f / fmaxf(sqrtf(tot), 1e-12f);
            const int row = m0 + lrow;
            if (row < M) {
                #pragma unroll
                for (int fn = 0; fn < 4; ++fn)
                    Out[(size_t)row * 256 + w * 64 + fn * 16 + l15] =
                        acc[fm][fn][r] * scale;
            }
        }
#undef STAGE_B
#undef STAGE_X
}

extern "C" void kernel_launch(void* const* d_in, const int* in_sizes, int n_in,
                              void* d_out, int out_size, void* d_ws, size_t ws_size,
                              hipStream_t stream)
{
    const float* X         = (const float*)d_in[0];
    const int*   sub_nodes = (const int*)d_in[1];
    const int*   nbr       = (const int*)d_in[2];
    const int*   g2s       = (const int*)d_in[3];
    const float* Wn        = (const float*)d_in[4];
    const float* bn        = (const float*)d_in[5];
    const float* Wf        = (const float*)d_in[6];
    const float* bfin      = (const float*)d_in[7];
    float*       out       = (float*)d_out;

    const int M = out_size / 256;                 // 50000 rows

    // workspace (bf16): Xb | Wnb | Wfb
    u16* Xb  = (u16*)d_ws;
    u16* Wnb = Xb  + (size_t)M * 256;
    u16* Wfb = Wnb + 65536;

    const int nx4 = M * 64;                       // float4 count of X
    const int castTotal = nx4 + 16384 + 32768;
    k_cast<<<(castTotal + 255) / 256, 256, 0, stream>>>(X, Wn, Wf, Xb, Wnb, Wfb, nx4);

    const int fBlocks = (M + 31) / 32;            // 1563 blocks
    k_fused<<<fBlocks, 256, 0, stream>>>(Xb, sub_nodes, nbr, g2s,
                                         Wnb, bn, Wfb, bfin, out, M);
}

// Round 16
// 125.615 us; speedup vs baseline: 1.1161x; 1.1161x over previous
//
#include <hip/hip_runtime.h>
#include <hip/hip_bf16.h>

#define KNBR 20
typedef unsigned short u16;
typedef __attribute__((ext_vector_type(8))) short bf16x8;   // 8 bf16 = 4 VGPR
typedef __attribute__((ext_vector_type(4))) float f32x4;    // MFMA C/D frag

// async global->LDS, 16B/lane; LDS dest wave-uniform base + lane*16 (m104)
#define GLDS16(gsrc, ldst)                                                     \
    __builtin_amdgcn_global_load_lds(                                          \
        (const __attribute__((address_space(1))) unsigned int*)(const void*)(gsrc), \
        (__attribute__((address_space(3))) unsigned int*)(void*)(ldst), 16, 0, 0)

// ---- runtime index-width detection (proven round 5) ----
__device__ __forceinline__ bool idx_is64(const unsigned int* w) {
    return (w[1] | w[3] | w[5] | w[7] | w[9] | w[11] | w[13] | w[15]) == 0u;
}
__device__ __forceinline__ int idx_at(const int* p, bool is64, long long i) {
    return is64 ? p[2 * i] : p[i];
}
__device__ __forceinline__ u16 f2bf(float x) {
    union { __hip_bfloat16 b; u16 u; } cv;
    cv.b = __float2bfloat16(x);
    return cv.u;
}
__device__ __forceinline__ float blo2f(unsigned int w) {
    union { float f; unsigned int i; } c; c.i = w << 16; return c.f;
}
__device__ __forceinline__ float bhi2f(unsigned int w) {
    union { float f; unsigned int i; } c; c.i = w & 0xffff0000u; return c.f;
}

// ---------------- K0: all fp32->bf16 casts in one kernel ----------------
__global__ void __launch_bounds__(256) k_cast(
    const float* __restrict__ X, const float* __restrict__ Wn,
    const float* __restrict__ Wf, u16* __restrict__ Xb,
    u16* __restrict__ Wnb, u16* __restrict__ Wfb, int nx4)
{
    const int i = blockIdx.x * 256 + threadIdx.x;
    const float4* src; ushort4* dst; int j;
    if (i < nx4)                     { src = (const float4*)X;  dst = (ushort4*)Xb;  j = i; }
    else if (i < nx4 + 16384)        { src = (const float4*)Wn; dst = (ushort4*)Wnb; j = i - nx4; }
    else if (i < nx4 + 16384 + 32768){ src = (const float4*)Wf; dst = (ushort4*)Wfb; j = i - nx4 - 16384; }
    else return;
    const float4 v = src[j];
    ushort4 o;
    o.x = f2bf(v.x); o.y = f2bf(v.y); o.z = f2bf(v.z); o.w = f2bf(v.w);
    dst[j] = o;
}

// ---------------- K1: fused gather+mean -> GEMM1 -> GEMM2 -> normalize ------
// Round-16: BM=64 (round-14 tile, best @129us) but 512 thr = 8 waves (2Mx4N):
// same 73KB LDS -> still 2 blocks/CU, yet 4 waves/SIMD (2x round-14 TLP).
// Round-15 lesson: shrinking BM halves MFMA-per-staged-byte -> regression;
// adding waves at constant tile does not. Gather row-loop unroll 2 for MLP
// (VGPR free: occupancy is LDS-limited; cap 128 via launch_bounds(512,4)).
__global__ void __launch_bounds__(512, 4) k_fused(
    const u16* __restrict__ Xb, const int* __restrict__ sub_nodes,
    const int* __restrict__ nbr, const int* __restrict__ g2s,
    const u16* __restrict__ Wnb, const float* __restrict__ bn,
    const u16* __restrict__ Wfb, const float* __restrict__ bfin,
    float* __restrict__ Out, int M)
{
    __shared__ u16 mh[64 * 256];                 // 32KB: mean, then h
    __shared__ u16 Bs[2][256 * 32];              // 16KB x2
    __shared__ u16 Xs[2][64 * 32];               // 4KB x2
    __shared__ __align__(16) float sums[64][4];  // 1KB

    const int t    = threadIdx.x;
    const int lane = t & 63;
    const int w    = t >> 6;             // wave 0..7
    const int wm   = w >> 2;             // 0..1 (M dir, 32 rows)
    const int wn   = w & 3;              // 0..3 (N dir, 64 cols)
    const int l15  = lane & 15;
    const int lk8  = (lane >> 4) << 3;   // 0,8,16,24
    const int rsub = (lane >> 4) << 2;   // 0,4,8,12
    const int r7   = l15 & 7;
    const int r3   = l15 & 3;
    const int sRow = lane >> 2;          // staging row-in-group 0..15
    const int sSlot= lane & 3;           // staging chunk 0..3
    const int m0   = blockIdx.x * 64;

// stage 16KB B-tile (256 rows x 32k): 8 waves x 2 passes, src chunk-swz c^(r&3)
#define STAGE_B(buf, Bp, KT, tt) do {                                          \
    _Pragma("unroll")                                                          \
    for (int rp_ = 0; rp_ < 2; ++rp_) {                                        \
        const int rr_ = rp_ * 128 + w * 16 + sRow;                             \
        const int cc_ = sSlot ^ (rr_ & 3);                                     \
        GLDS16(Bp + (size_t)rr_ * KT + (tt) * 32 + cc_ * 8,                    \
               &Bs[buf][rp_ * 4096 + w * 512]);                                \
    } } while (0)

// stage 4KB X-tile (64 rows x 32k): waves 0-3 only
#define STAGE_X(buf, tt) do {                                                  \
    if (w < 4) {                                                               \
        const int rl_ = w * 16 + sRow;                                         \
        int rg_ = m0 + rl_; rg_ = (rg_ < M) ? rg_ : (M - 1);                   \
        const int cc_ = sSlot ^ (rl_ & 3);                                     \
        GLDS16(Xb + (size_t)rg_ * 256 + (tt) * 32 + cc_ * 8, &Xs[buf][w * 512]); \
    } } while (0)

    // prefetch GEMM1 B step 0 under the gather
    STAGE_B(0, Wnb, 256, 0);

    // ---- phase G: gather-mean, 8 waves x 2 rows/iter x 4 iters = 64 rows ---
    {
        const bool is64 = idx_is64((const unsigned int*)nbr);
        const int half = lane >> 5;
        const int l31  = lane & 31;
        const int sb   = half << 5;
        #pragma unroll 2
        for (int j = 0; j < 4; ++j) {
            const int rl  = w * 8 + j * 2 + half;
            const int row = m0 + rl;
            const int rowc = (row < M) ? row : (M - 1);
            const int g = idx_at(sub_nodes, is64, rowc);
            int s_my = rowc;
            if (l31 < KNBR) {
                int nid = idx_at(nbr, is64, (long long)g * KNBR + l31);
                int s   = idx_at(g2s, is64, nid);
                s_my = (s < 0) ? rowc : s;
            }
            float a0=0.f,a1=0.f,a2=0.f,a3=0.f,a4=0.f,a5=0.f,a6=0.f,a7=0.f;
            #pragma unroll
            for (int k = 0; k < KNBR; ++k) {
                const int sk = __shfl(s_my, sb + k, 64);
                const uint4 v = *(const uint4*)(Xb + (size_t)sk * 256 + l31 * 8);
                a0 += blo2f(v.x); a1 += bhi2f(v.x);
                a2 += blo2f(v.y); a3 += bhi2f(v.y);
                a4 += blo2f(v.z); a5 += bhi2f(v.z);
                a6 += blo2f(v.w); a7 += bhi2f(v.w);
            }
            const float inv = 1.0f / (float)KNBR;
            uint4 o;
            o.x = (unsigned)f2bf(a0*inv) | ((unsigned)f2bf(a1*inv) << 16);
            o.y = (unsigned)f2bf(a2*inv) | ((unsigned)f2bf(a3*inv) << 16);
            o.z = (unsigned)f2bf(a4*inv) | ((unsigned)f2bf(a5*inv) << 16);
            o.w = (unsigned)f2bf(a6*inv) | ((unsigned)f2bf(a7*inv) << 16);
            *(uint4*)&mh[rl * 256 + ((l31 ^ (rl & 7)) << 3)] = o;
        }
    }
    __syncthreads();   // mean in LDS + B1[0] staged

    // ---- phase 1: h = relu(mean @ Wn^T + bn), h -> mh (in place) ----------
    f32x4 acc[2][4];
    #pragma unroll
    for (int i = 0; i < 2; ++i)
        #pragma unroll
        for (int j = 0; j < 4; ++j)
            acc[i][j] = (f32x4)(0.f);

    #pragma unroll
    for (int tt = 0; tt < 8; ++tt) {
        const int cur = tt & 1;
        if (tt < 7) STAGE_B(cur ^ 1, Wnb, 256, tt + 1);
        bf16x8 af[2], bfr[4];
        #pragma unroll
        for (int fm = 0; fm < 2; ++fm)
            af[fm] = *(const bf16x8*)&mh[(wm*32 + fm*16 + l15) * 256 +
                                         (((tt*4 + (lk8 >> 3)) ^ r7) << 3)];
        #pragma unroll
        for (int fn = 0; fn < 4; ++fn)
            bfr[fn] = *(const bf16x8*)&Bs[cur][(wn*64 + fn*16 + l15) * 32 +
                                              (((lk8 >> 3) ^ r3) << 3)];
        #pragma unroll
        for (int fm = 0; fm < 2; ++fm)
            #pragma unroll
            for (int fn = 0; fn < 4; ++fn)
                acc[fm][fn] = __builtin_amdgcn_mfma_f32_16x16x32_bf16(
                    af[fm], bfr[fn], acc[fm][fn], 0, 0, 0);
        __syncthreads();
    }

    // prefetch GEMM2 step 0 (Bs[0] free; Xs untouched so far)
    STAGE_B(0, Wfb, 512, 0);
    STAGE_X(0, 0);

    // write h into mh (all mean reads completed at loop-end barrier)
    #pragma unroll
    for (int fn = 0; fn < 4; ++fn) {
        const int col = wn * 64 + fn * 16 + l15;
        const float bv = bn[col];
        #pragma unroll
        for (int fm = 0; fm < 2; ++fm)
            #pragma unroll
            for (int r = 0; r < 4; ++r) {
                const int row = wm * 32 + fm * 16 + rsub + r;
                const float v = fmaxf(acc[fm][fn][r] + bv, 0.f);
                mh[row * 256 + ((((col >> 3) ^ (row & 7))) << 3) + (col & 7)] = f2bf(v);
            }
    }
    __syncthreads();   // h visible + GEMM2 step-0 tiles staged

    // ---- phase 2: out = normalize(relu([X|h] @ Wf^T + bf)) ----------------
    #pragma unroll
    for (int i = 0; i < 2; ++i)
        #pragma unroll
        for (int j = 0; j < 4; ++j)
            acc[i][j] = (f32x4)(0.f);

    #pragma unroll
    for (int tt = 0; tt < 16; ++tt) {
        const int cur = tt & 1;
        if (tt < 15) {
            STAGE_B(cur ^ 1, Wfb, 512, tt + 1);
            if (tt + 1 < 8) STAGE_X(cur ^ 1, tt + 1);
        }
        bf16x8 af[2], bfr[4];
        if (tt < 8) {
            #pragma unroll
            for (int fm = 0; fm < 2; ++fm)
                af[fm] = *(const bf16x8*)&Xs[cur][(wm*32 + fm*16 + l15) * 32 +
                                                  (((lk8 >> 3) ^ r3) << 3)];
        } else {
            #pragma unroll
            for (int fm = 0; fm < 2; ++fm)
                af[fm] = *(const bf16x8*)&mh[(wm*32 + fm*16 + l15) * 256 +
                                             ((((tt-8)*4 + (lk8 >> 3)) ^ r7) << 3)];
        }
        #pragma unroll
        for (int fn = 0; fn < 4; ++fn)
            bfr[fn] = *(const bf16x8*)&Bs[cur][(wn*64 + fn*16 + l15) * 32 +
                                              (((lk8 >> 3) ^ r3) << 3)];
        #pragma unroll
        for (int fm = 0; fm < 2; ++fm)
            #pragma unroll
            for (int fn = 0; fn < 4; ++fn)
                acc[fm][fn] = __builtin_amdgcn_mfma_f32_16x16x32_bf16(
                    af[fm], bfr[fn], acc[fm][fn], 0, 0, 0);
        __syncthreads();
    }

    // epilogue: bias + relu + row-L2-normalize + fp32 store
    float part[2][4];
    #pragma unroll
    for (int fm = 0; fm < 2; ++fm)
        #pragma unroll
        for (int r = 0; r < 4; ++r)
            part[fm][r] = 0.f;
    #pragma unroll
    for (int fn = 0; fn < 4; ++fn) {
        const float bv = bfin[wn * 64 + fn * 16 + l15];
        #pragma unroll
        for (int fm = 0; fm < 2; ++fm)
            #pragma unroll
            for (int r = 0; r < 4; ++r) {
                const float v = fmaxf(acc[fm][fn][r] + bv, 0.f);
                acc[fm][fn][r] = v;
                part[fm][r] += v * v;
            }
    }
    #pragma unroll
    for (int fm = 0; fm < 2; ++fm)
        #pragma unroll
        for (int r = 0; r < 4; ++r) {
            float s = part[fm][r];
            s += __shfl_xor(s, 1, 64);
            s += __shfl_xor(s, 2, 64);
            s += __shfl_xor(s, 4, 64);
            s += __shfl_xor(s, 8, 64);
            part[fm][r] = s;
        }
    if (l15 == 0) {
        #pragma unroll
        for (int fm = 0; fm < 2; ++fm)
            #pragma unroll
            for (int r = 0; r < 4; ++r)
                sums[wm * 32 + fm * 16 + rsub + r][wn] = part[fm][r];
    }
    __syncthreads();
    #pragma unroll
    for (int fm = 0; fm < 2; ++fm)
        #pragma unroll
        for (int r = 0; r < 4; ++r) {
            const int lrow = wm * 32 + fm * 16 + rsub + r;
            const f32x4 sv = *(const f32x4*)&sums[lrow][0];
            const float tot = sv.x + sv.y + sv.z + sv.w;
            const float scale = 1.f / fmaxf(sqrtf(tot), 1e-12f);
            const int row = m0 + lrow;
            if (row < M) {
                #pragma unroll
                for (int fn = 0; fn < 4; ++fn)
                    Out[(size_t)row * 256 + wn * 64 + fn * 16 + l15] =
                        acc[fm][fn][r] * scale;
            }
        }
#undef STAGE_B
#undef STAGE_X
}

extern "C" void kernel_launch(void* const* d_in, const int* in_sizes, int n_in,
                              void* d_out, int out_size, void* d_ws, size_t ws_size,
                              hipStream_t stream)
{
    const float* X         = (const float*)d_in[0];
    const int*   sub_nodes = (const int*)d_in[1];
    const int*   nbr       = (const int*)d_in[2];
    const int*   g2s       = (const int*)d_in[3];
    const float* Wn        = (const float*)d_in[4];
    const float* bn        = (const float*)d_in[5];
    const float* Wf        = (const float*)d_in[6];
    const float* bfin      = (const float*)d_in[7];
    float*       out       = (float*)d_out;

    const int M = out_size / 256;                 // 50000 rows

    // workspace (bf16): Xb | Wnb | Wfb
    u16* Xb  = (u16*)d_ws;
    u16* Wnb = Xb  + (size_t)M * 256;
    u16* Wfb = Wnb + 65536;

    const int nx4 = M * 64;                       // float4 count of X
    const int castTotal = nx4 + 16384 + 32768;
    k_cast<<<(castTotal + 255) / 256, 256, 0, stream>>>(X, Wn, Wf, Xb, Wnb, Wfb, nx4);

    const int fBlocks = (M + 63) / 64;            // 782 blocks
    k_fused<<<fBlocks, 512, 0, stream>>>(Xb, sub_nodes, nbr, g2s,
                                         Wnb, bn, Wfb, bfin, out, M);
}